// Round 1
// baseline (27.169 us; speedup 1.0000x reference)
//
#include <hip/hip_runtime.h>

constexpr int N_SAMP = 2048;
constexpr int T_DIM  = 256;
constexpr int D_DIM  = 64;
constexpr int NBINS  = 64;

// One block per t. 1024 threads. LDS histogram for all 64 d at this t,
// then fused partial-loss reduction against densities.
__global__ __launch_bounds__(1024) void histo_loss_kernel(
    const float* __restrict__ x,      // [N, T, D]
    const float* __restrict__ dens,   // [T, D, NBINS]
    const float* __restrict__ bmin,   // [T, D]
    const float* __restrict__ bmax,   // [T, D]
    float* __restrict__ partial)      // [T]
{
    __shared__ unsigned int hist[D_DIM * NBINS];   // 16 KB
    const int t   = blockIdx.x;
    const int tid = threadIdx.x;

    for (int i = tid; i < D_DIM * NBINS; i += 1024) hist[i] = 0u;

    // Each thread owns 4 consecutive d-columns (d0..d0+3), fixed for all n.
    const int c  = tid & 15;   // which float4 within the 64-float row
    const int r  = tid >> 4;   // row offset within a 64-row chunk
    const int d0 = c * 4;

    const float4 a4 = *reinterpret_cast<const float4*>(bmin + t * D_DIM + d0);
    const float4 b4 = *reinterpret_cast<const float4*>(bmax + t * D_DIM + d0);
    const float a[4] = {a4.x, a4.y, a4.z, a4.w};
    const float b[4] = {b4.x, b4.y, b4.z, b4.w};
    float s[4];
#pragma unroll
    for (int j = 0; j < 4; ++j) s[j] = (float)NBINS / (b[j] - a[j]);

    __syncthreads();

    const float4* __restrict__ x4 = reinterpret_cast<const float4*>(x);
    const size_t row4 = (size_t)(T_DIM * D_DIM / 4);         // 4096 float4 per n
    const size_t base = (size_t)r * row4 + (size_t)t * (D_DIM / 4) + (size_t)c;

#pragma unroll 4
    for (int it = 0; it < N_SAMP / 64; ++it) {
        float4 v4 = x4[base + (size_t)it * 64 * row4];
        float v[4] = {v4.x, v4.y, v4.z, v4.w};
#pragma unroll
        for (int j = 0; j < 4; ++j) {
            float vv = v[j];
            if (vv >= a[j] && vv <= b[j]) {
                int idx = (int)floorf((vv - a[j]) * s[j]);
                idx = idx < 0 ? 0 : (idx > NBINS - 1 ? NBINS - 1 : idx);
                atomicAdd(&hist[(d0 + j) * NBINS + idx], 1u);
            }
        }
    }
    __syncthreads();

    // Partial loss for this t: sum_f |hist[f]/N - dens[t][f]|
    const float invN = 1.0f / (float)N_SAMP;
    const float* __restrict__ db = dens + (size_t)t * (D_DIM * NBINS);
    float sum = 0.0f;
#pragma unroll
    for (int k = 0; k < (D_DIM * NBINS) / 1024; ++k) {
        int f = k * 1024 + tid;
        sum += fabsf((float)hist[f] * invN - db[f]);
    }
#pragma unroll
    for (int off = 32; off > 0; off >>= 1) sum += __shfl_down(sum, off, 64);

    __shared__ float wpart[16];
    if ((tid & 63) == 0) wpart[tid >> 6] = sum;
    __syncthreads();
    if (tid < 16) {
        float v = wpart[tid];
#pragma unroll
        for (int off = 8; off > 0; off >>= 1) v += __shfl_down(v, off, 16);
        if (tid == 0) partial[t] = v;
    }
}

__global__ __launch_bounds__(256) void histo_final_reduce(
    const float* __restrict__ partial, float* __restrict__ out)
{
    const int tid = threadIdx.x;
    float v = partial[tid];
#pragma unroll
    for (int off = 32; off > 0; off >>= 1) v += __shfl_down(v, off, 64);
    __shared__ float wpart[4];
    if ((tid & 63) == 0) wpart[tid >> 6] = v;
    __syncthreads();
    if (tid == 0) {
        float tot = (wpart[0] + wpart[1]) + (wpart[2] + wpart[3]);
        out[0] = tot * (1.0f / (float)(T_DIM * D_DIM * NBINS));
    }
}

extern "C" void kernel_launch(void* const* d_in, const int* in_sizes, int n_in,
                              void* d_out, int out_size, void* d_ws, size_t ws_size,
                              hipStream_t stream)
{
    const float* x    = (const float*)d_in[0];   // x_fake  [N,T,D]
    const float* dens = (const float*)d_in[1];   // densities [T,D,NBINS]
    const float* bmin = (const float*)d_in[2];   // [T,D]
    const float* bmax = (const float*)d_in[3];   // [T,D]
    float* out     = (float*)d_out;
    float* partial = (float*)d_ws;               // 256 floats

    histo_loss_kernel<<<T_DIM, 1024, 0, stream>>>(x, dens, bmin, bmax, partial);
    histo_final_reduce<<<1, 256, 0, stream>>>(partial, out);
}